// Round 15
// baseline (375.150 us; speedup 1.0000x reference)
//
#include <hip/hip_runtime.h>
#include <hip/hip_bf16.h>

typedef unsigned short ushortT;
typedef unsigned int uintT;
typedef __attribute__((ext_vector_type(8))) short bf16x8;
typedef __attribute__((ext_vector_type(4))) float f32x4;
typedef __attribute__((ext_vector_type(4))) unsigned short us4;
typedef __attribute__((ext_vector_type(8))) unsigned short us8;

__device__ __forceinline__ ushortT f2bf(float f) {
    union { float f; uintT u; } x; x.f = f;
    uintT r = x.u + 0x7fffu + ((x.u >> 16) & 1u);
    return (ushortT)(r >> 16);
}
__device__ __forceinline__ float bf2f(ushortT u) {
    union { uintT u; float f; } x; x.u = ((uintT)u) << 16; return x.f;
}

#define ZLD 260      // k_z LDS row stride (0-conflict family)
#define KTOT 5120    // K = 10 q * 512 v

// ---------------------------------------------------------------------------
// K0: column-softmax of W1/W2, e = emb @ sW, row-normalize.  grid=2 (e1, e2)
// ---------------------------------------------------------------------------
__global__ __launch_bounds__(256) void k_embed(const float* __restrict__ emb,
                                               const float* __restrict__ W1,
                                               const float* __restrict__ W2,
                                               float* __restrict__ e1,
                                               float* __restrict__ e2) {
    __shared__ float sW[800];
    __shared__ float sWs[800];
    const float* W = (blockIdx.x == 0) ? W1 : W2;
    float* e = (blockIdx.x == 0) ? e1 : e2;
    int tid = threadIdx.x;
    for (int i = tid; i < 800; i += 256) sW[i] = W[i];
    __syncthreads();
    if (tid < 20) {
        float mx = -1e30f;
        for (int i = 0; i < 40; ++i) mx = fmaxf(mx, sW[i * 20 + tid]);
        float s = 0.f;
        for (int i = 0; i < 40; ++i) s += __expf(sW[i * 20 + tid] - mx);
        float inv = 1.f / s;
        for (int i = 0; i < 40; ++i) sWs[i * 20 + tid] = __expf(sW[i * 20 + tid] - mx) * inv;
    }
    __syncthreads();
    for (int row = tid; row < 512; row += 256) {
        float acc[20];
        #pragma unroll
        for (int j = 0; j < 20; ++j) acc[j] = 0.f;
        for (int i = 0; i < 40; ++i) {
            float ev = emb[row * 40 + i];
            #pragma unroll
            for (int j = 0; j < 20; ++j) acc[j] += ev * sWs[i * 20 + j];
        }
        float s = 0.f;
        #pragma unroll
        for (int j = 0; j < 20; ++j) s += acc[j] * acc[j];
        float scale = 1.f / (sqrtf(s) + 1e-8f);
        #pragma unroll
        for (int j = 0; j < 20; ++j) e[row * 20 + j] = acc[j] * scale;
    }
}

// ---------------------------------------------------------------------------
// K1: A[v][w] = adj>0 ? e1[v].e2[w] + adj : 9e-15 ; d[v] = 1/sqrt(rowsum)
// ---------------------------------------------------------------------------
__global__ __launch_bounds__(256) void k_adj(const float* __restrict__ adj,
                                             const float* __restrict__ e1,
                                             const float* __restrict__ e2,
                                             float* __restrict__ A,
                                             float* __restrict__ d) {
    int v = blockIdx.x, tid = threadIdx.x;
    __shared__ float ev[20];
    if (tid < 20) ev[tid] = e1[v * 20 + tid];
    __syncthreads();
    float local = 0.f;
    for (int w = tid; w < 512; w += 256) {
        float dot = 0.f;
        #pragma unroll
        for (int j = 0; j < 20; ++j) dot += ev[j] * e2[w * 20 + j];
        float av = adj[v * 512 + w];
        float Av = (av > 0.f) ? (dot + av) : 9e-15f;
        A[v * 512 + w] = Av;
        local += Av;
    }
    __shared__ float red[256];
    red[tid] = local;
    __syncthreads();
    for (int s = 128; s > 0; s >>= 1) {
        if (tid < s) red[tid] += red[tid + s];
        __syncthreads();
    }
    if (tid == 0) d[v] = 1.f / sqrtf(red[0]);
}

// ---------------------------------------------------------------------------
// K2 (merged): blocks 0..511: P slot0 = I, slot1 = Ls^T.  blocks 512..671: Wq.
// ---------------------------------------------------------------------------
__global__ __launch_bounds__(256) void k_m(const float* __restrict__ A,
                                           const float* __restrict__ d,
                                           ushortT* __restrict__ P,
                                           const float* __restrict__ mlp_w,
                                           ushortT* __restrict__ Wq) {
    int bx = blockIdx.x, tid = threadIdx.x;
    if (bx < 512) {
        int w = bx;
        float dw = d[w];
        for (int v = tid; v < 512; v += 256) {
            float val = -d[v] * dw * A[v * 512 + w];
            P[512 * 512 + w * 512 + v] = f2bf(val);
            P[w * 512 + v] = (v == w) ? (ushortT)0x3F80 : (ushortT)0;
        }
    } else {
        int idx = (bx - 512) * 256 + tid;
        if (idx >= 10 * 64 * 64) return;
        int q = idx >> 12, rem = idx & 4095, o = rem >> 6, c = rem & 63;
        float v;
        if (q == 0) {
            v = 0.f;
            #pragma unroll
            for (int k = 0; k < 4; ++k) v += mlp_w[o * 832 + k * 64 + c];
        } else {
            v = mlp_w[o * 832 + (q + 3) * 64 + c];
        }
        Wq[idx] = f2bf(v);
    }
}

// ---------------------------------------------------------------------------
// k_prep: x (f32, [b][v][t][c]) -> xbf (bf16, [bt][v][c]). grid = 12288.
// Coalesced f32 read; fixes k_z's 3KB-strided uncoalesced x access.
// ---------------------------------------------------------------------------
__global__ __launch_bounds__(256) void k_prep(const float* __restrict__ x,
                                              ushortT* __restrict__ xbf) {
    size_t i = (size_t)blockIdx.x * 256 + threadIdx.x;
    int c = (int)(i & 15) * 4;
    int v = (int)((i >> 4) & 511);
    int bt = (int)(i >> 13);            // b*12 + t
    int b = bt / 12, t = bt - b * 12;
    f32x4 f = *(const f32x4*)(x + (((size_t)b * 512 + v) * 12 + t) * 64 + c);
    us4 o = { f2bf(f[0]), f2bf(f[1]), f2bf(f[2]), f2bf(f[3]) };
    *(us4*)(xbf + ((size_t)bt * 512 + v) * 64 + c) = o;
}

// ---------------------------------------------------------------------------
// kz_body: build B' = Z^T rows for one (btl, 256-v chunk).
// Z[n = btl*64+o][k = q*512+v] = sum_c x[bt,v,c]*Wq[o,c]
// XBF=true: dense bf16 reads from xbf. XBF=false: strided f32 fallback.
// ---------------------------------------------------------------------------
template<bool XBF>
__device__ void kz_body(const float* __restrict__ x,
                        const ushortT* __restrict__ xbf,
                        const ushortT* __restrict__ Wq,
                        ushortT* __restrict__ Z,
                        int kzbid, int slab0) {
    __shared__ ushortT Zl[64 * ZLD];
    int btl = kzbid >> 1, chunk = kzbid & 1;
    int bt = slab0 + btl;
    int b = bt / 12, t = bt - b * 12;
    int tid = threadIdx.x, wave = tid >> 6, lane = tid & 63;
    int lr = lane & 15, lg = lane >> 4;

    bf16x8 xn[4][2];
    const float* xb = x + ((size_t)b * 512 * 12 + t) * 64;
    const ushortT* xq = xbf + (size_t)bt * 512 * 64;
    #pragma unroll
    for (int vt = 0; vt < 4; ++vt) {
        int vrow = chunk * 256 + wave * 64 + vt * 16 + lr;
        if (XBF) {
            xn[vt][0] = *(const bf16x8*)(xq + vrow * 64 + lg * 8);
            xn[vt][1] = *(const bf16x8*)(xq + vrow * 64 + 32 + lg * 8);
        } else {
            const float* px = xb + (size_t)vrow * 768 + lg * 8;
            f32x4 f0 = *(const f32x4*)px;
            f32x4 f1 = *(const f32x4*)(px + 4);
            f32x4 f2 = *(const f32x4*)(px + 32);
            f32x4 f3 = *(const f32x4*)(px + 36);
            bf16x8 v0, v1;
            v0[0] = (short)f2bf(f0[0]); v0[1] = (short)f2bf(f0[1]);
            v0[2] = (short)f2bf(f0[2]); v0[3] = (short)f2bf(f0[3]);
            v0[4] = (short)f2bf(f1[0]); v0[5] = (short)f2bf(f1[1]);
            v0[6] = (short)f2bf(f1[2]); v0[7] = (short)f2bf(f1[3]);
            v1[0] = (short)f2bf(f2[0]); v1[1] = (short)f2bf(f2[1]);
            v1[2] = (short)f2bf(f2[2]); v1[3] = (short)f2bf(f2[3]);
            v1[4] = (short)f2bf(f3[0]); v1[5] = (short)f2bf(f3[1]);
            v1[6] = (short)f2bf(f3[2]); v1[7] = (short)f2bf(f3[3]);
            xn[vt][0] = v0;
            xn[vt][1] = v1;
        }
    }

    #pragma unroll 1
    for (int q = 0; q < 10; ++q) {
        const ushortT* wqp = Wq + q * 4096;
        #pragma unroll
        for (int ot = 0; ot < 4; ++ot) {
            int o = ot * 16 + lr;
            bf16x8 wf0 = *(const bf16x8*)(wqp + o * 64 + lg * 8);
            bf16x8 wf1 = *(const bf16x8*)(wqp + o * 64 + 32 + lg * 8);
            #pragma unroll
            for (int vt = 0; vt < 4; ++vt) {
                f32x4 z = {};
                z = __builtin_amdgcn_mfma_f32_16x16x32_bf16(xn[vt][0], wf0, z, 0, 0, 0);
                z = __builtin_amdgcn_mfma_f32_16x16x32_bf16(xn[vt][1], wf1, z, 0, 0, 0);
                us4 pk = { f2bf(z[0]), f2bf(z[1]), f2bf(z[2]), f2bf(z[3]) };
                *(us4*)&Zl[o * ZLD + wave * 64 + vt * 16 + lg * 4] = pk;
            }
        }
        __syncthreads();
        size_t kbase = (size_t)q * 512 + chunk * 256;
        #pragma unroll
        for (int j = 0; j < 8; ++j) {
            int flat = j * 256 + tid;
            int o = flat >> 5, slot = flat & 31;
            us4 lo = *(const us4*)&Zl[o * ZLD + slot * 8];
            us4 hi = *(const us4*)&Zl[o * ZLD + slot * 8 + 4];
            us8 val = { lo[0], lo[1], lo[2], lo[3], hi[0], hi[1], hi[2], hi[3] };
            *(us8*)&Z[(size_t)(btl * 64 + o) * KTOT + kbase + slot * 8] = val;
        }
        __syncthreads();
    }
}

template<bool XBF>
__global__ __launch_bounds__(256) void k_z(const float* __restrict__ x,
                                           const ushortT* __restrict__ xbf,
                                           const ushortT* __restrict__ Wq,
                                           ushortT* __restrict__ Z,
                                           int slab0) {
    kz_body<XBF>(x, xbf, Wq, Z, blockIdx.x, slab0);
}

// ---------------------------------------------------------------------------
// 512x512x512 bf16 MFMA GEMM (+Chebyshev epilogue). Supports a second
// independent GEMM in blocks 64..127 (A2/B2/out3, mode 0).
// ---------------------------------------------------------------------------
__global__ __launch_bounds__(256) void k_gemm512(const ushortT* __restrict__ A,
                                                 const ushortT* __restrict__ B,
                                                 ushortT* __restrict__ out1,
                                                 ushortT* __restrict__ out2,
                                                 int mode,
                                                 const ushortT* __restrict__ aux,
                                                 const ushortT* __restrict__ A2,
                                                 const ushortT* __restrict__ B2,
                                                 ushortT* __restrict__ out3) {
    int bx = blockIdx.x;
    if (bx >= 64) { A = A2; B = B2; out1 = out3; out2 = nullptr; mode = 0; bx -= 64; }
    int wave = threadIdx.x >> 6, lane = threadIdx.x & 63;
    int lr = lane & 15, lg = lane >> 4;
    int mbase = (bx >> 3) * 64;
    int nbase = (bx & 7) * 64 + wave * 16;
    f32x4 acc[4] = {};
    for (int kk = 0; kk < 16; ++kk) {
        int k0 = kk * 32 + lg * 8;
        bf16x8 bfr;
        #pragma unroll
        for (int j = 0; j < 8; ++j) bfr[j] = (short)B[(k0 + j) * 512 + nbase + lr];
        #pragma unroll
        for (int wt = 0; wt < 4; ++wt) {
            bf16x8 af = *(const bf16x8*)(A + (mbase + wt * 16 + lr) * 512 + k0);
            acc[wt] = __builtin_amdgcn_mfma_f32_16x16x32_bf16(af, bfr, acc[wt], 0, 0, 0);
        }
    }
    #pragma unroll
    for (int wt = 0; wt < 4; ++wt)
        #pragma unroll
        for (int r = 0; r < 4; ++r) {
            int row = mbase + wt * 16 + lg * 4 + r;
            int col = nbase + lr;
            float v = acc[wt][r];
            out1[row * 512 + col] = f2bf(v);
            if (mode == 1) out2[row * 512 + col] = f2bf(2.f * v - (row == col ? 1.f : 0.f));
            else if (mode == 2) out2[row * 512 + col] = f2bf(4.f * v - 3.f * bf2f(aux[row * 512 + col]));
        }
}

// ---------------------------------------------------------------------------
// k_big v4: ring-4 + SINGLE barrier per phase, R11's full 3-phase flight cover.
//   phase kt: vmcnt(8) ; s_barrier ; ds_read buf[kt&3] ; issue stage(kt+3)
//             into buf[(kt+3)&3] ; 16 MFMA.
//   RAW: vmcnt(8) at top — stages kt+1,kt+2 in flight, kt proven resident.
//   WAR: buf (kt+3)&3 = (kt-1)&3; its readers' ds_reads were register-complete
//   before their phase-kt top barrier (reads feed MFMAs which precede it).
// ---------------------------------------------------------------------------
__global__ __launch_bounds__(256) void k_big(const ushortT* __restrict__ P,
                                             const ushortT* __restrict__ Z,
                                             const float* __restrict__ x,
                                             const float* __restrict__ bias,
                                             float* __restrict__ out,
                                             int slab0) {
    __shared__ ushortT SA[4][4096];   // [ring][128 m x 32 k] linear
    __shared__ ushortT SB[4][4096];   // [ring][128 n x 32 k] linear
    int nwg = (int)gridDim.x;
    int bid = (int)blockIdx.x;
    int cpx = nwg >> 3;                               // blocks per XCD chunk
    int lbid = (bid & 7) * cpx + (bid >> 3);          // bijective (nwg%8==0)
    int mblk = lbid & 3;                              // m fastest -> same XCD
    int nblk = lbid >> 2;
    int mbase = mblk * 128;
    int n0 = nblk * 128;
    int tid = threadIdx.x, wave = tid >> 6, lane = tid & 63;
    int lr = lane & 15, lg = lane >> 4;
    int wm = wave >> 1, wn = wave & 1;
    int srow = tid >> 2, sg = tid & 3;                // staging row/group

    f32x4 acc[4][4] = {};

    // stage K-step kt into ring buffer buf (A: P rows, B: Z rows). 4 VMEM/wave.
    auto stage = [&](int kt, int buf) {
        int q = kt >> 4;
        int v0 = (kt & 15) * 32;
        const ushortT* Pk = P + (size_t)q * 262144 + v0 + sg * 8;
        const ushortT* Zk = Z + (size_t)kt * 32 + sg * 8;
        #pragma unroll
        for (int i = 0; i < 2; ++i) {
            int row = i * 64 + srow;
            __builtin_amdgcn_global_load_lds(Pk + (size_t)(mbase + row) * 512,
                                             &SA[buf][(i * 256 + wave * 64) * 8], 16, 0, 0);
            __builtin_amdgcn_global_load_lds(Zk + (size_t)(n0 + row) * KTOT,
                                             &SB[buf][(i * 256 + wave * 64) * 8], 16, 0, 0);
        }
    };

    // single-barrier phase. wsel: 0 -> vmcnt(8), 1 -> vmcnt(4), 2 -> vmcnt(0).
    auto phase = [&](int kt, int wsel) {
        if (wsel == 0)      asm volatile("s_waitcnt vmcnt(8)" ::: "memory");
        else if (wsel == 1) asm volatile("s_waitcnt vmcnt(4)" ::: "memory");
        else                asm volatile("s_waitcnt vmcnt(0)" ::: "memory");
        __builtin_amdgcn_sched_barrier(0);
        __builtin_amdgcn_s_barrier();          // all waves: kt data resident
        __builtin_amdgcn_sched_barrier(0);
        int buf = kt & 3;
        bf16x8 af[4], bfr[4];
        #pragma unroll
        for (int mt = 0; mt < 4; ++mt) {
            int m = wm * 64 + mt * 16 + lr;
            af[mt] = *(const bf16x8*)&SA[buf][m * 32 + lg * 8];
        }
        #pragma unroll
        for (int nt = 0; nt < 4; ++nt) {
            int n = wn * 64 + nt * 16 + lr;
            bfr[nt] = *(const bf16x8*)&SB[buf][n * 32 + lg * 8];
        }
        if (kt + 3 < 160) stage(kt + 3, (kt + 3) & 3);  // VMEM under MFMA
        __builtin_amdgcn_s_setprio(1);
        #pragma unroll
        for (int mt = 0; mt < 4; ++mt)
            #pragma unroll
            for (int nt = 0; nt < 4; ++nt)
                acc[mt][nt] = __builtin_amdgcn_mfma_f32_16x16x32_bf16(af[mt], bfr[nt], acc[mt][nt], 0, 0, 0);
        __builtin_amdgcn_s_setprio(0);
        __builtin_amdgcn_sched_barrier(0);
    };

    // prologue: fill 3 ring slots (12 loads/wave outstanding)
    stage(0, 0);
    __builtin_amdgcn_sched_barrier(0);
    stage(1, 1);
    __builtin_amdgcn_sched_barrier(0);
    stage(2, 2);
    __builtin_amdgcn_sched_barrier(0);

    #pragma unroll 1
    for (int kt = 0; kt < 158; ++kt) phase(kt, 0);
    phase(158, 1);
    phase(159, 2);

    // ---- epilogue: residual + bias + relu ----
    #pragma unroll
    for (int mt = 0; mt < 4; ++mt)
        #pragma unroll
        for (int nt = 0; nt < 4; ++nt)
            #pragma unroll
            for (int r = 0; r < 4; ++r) {
                int m = mbase + wm * 64 + mt * 16 + lg * 4 + r;   // w
                int nf = n0 + wn * 64 + nt * 16 + lr;
                int btl = nf >> 6, o = nf & 63;
                int bt = slab0 + btl;
                int bb = bt / 12, t = bt - bb * 12;
                size_t oi = (((size_t)bb * 512 + m) * 12 + t) * 64 + o;
                float v = acc[mt][nt][r] + x[oi] + bias[o];
                out[oi] = (v > 0.f) ? v : 0.f;
            }
}

// ---------------------------------------------------------------------------
// Fallback fused kernel (R9 structure, f32 x path) — used only if ws is tiny.
// ---------------------------------------------------------------------------
__global__ __launch_bounds__(256, 2) void k_main_fb(const float* __restrict__ x,
                                                    const ushortT* __restrict__ P,
                                                    const ushortT* __restrict__ Wq,
                                                    const float* __restrict__ bias,
                                                    float* __restrict__ out) {
    __shared__ ushortT Zt[64 * ZLD];
    const int SZ = 512 * 512;
    int bid = blockIdx.x;
    int slot = bid & 7, idx = bid >> 3;
    int half = slot >> 2;
    int bt = idx * 4 + (slot & 3);
    int b = bt / 12, tt = bt - b * 12;
    int tid = threadIdx.x, wave = tid >> 6, lane = tid & 63;
    int lr = lane & 15, lg = lane >> 4;
    int wbase = half * 256 + wave * 64;
    int vzb = wave * 64;
    const float* xqf = x + ((size_t)b * 512 * 12 + tt) * 64;

    f32x4 oacc[4][4] = {};
    bf16x8 xn[4][2];

    auto xload = [&](int ch) {
        #pragma unroll
        for (int vt = 0; vt < 4; ++vt) {
            int vrow = ch * 256 + vzb + vt * 16 + lr;
            const float* px = xqf + (size_t)vrow * 768 + lg * 8;
            f32x4 f0 = *(const f32x4*)px;
            f32x4 f1 = *(const f32x4*)(px + 4);
            f32x4 f2 = *(const f32x4*)(px + 32);
            f32x4 f3 = *(const f32x4*)(px + 36);
            bf16x8 v0, v1;
            v0[0] = (short)f2bf(f0[0]); v0[1] = (short)f2bf(f0[1]);
            v0[2] = (short)f2bf(f0[2]); v0[3] = (short)f2bf(f0[3]);
            v0[4] = (short)f2bf(f1[0]); v0[5] = (short)f2bf(f1[1]);
            v0[6] = (short)f2bf(f1[2]); v0[7] = (short)f2bf(f1[3]);
            v1[0] = (short)f2bf(f2[0]); v1[1] = (short)f2bf(f2[1]);
            v1[2] = (short)f2bf(f2[2]); v1[3] = (short)f2bf(f2[3]);
            v1[4] = (short)f2bf(f3[0]); v1[5] = (short)f2bf(f3[1]);
            v1[6] = (short)f2bf(f3[2]); v1[7] = (short)f2bf(f3[3]);
            xn[vt][0] = v0;
            xn[vt][1] = v1;
        }
    };
    auto zphase = [&](int q) {
        const ushortT* wqp = Wq + q * 4096;
        #pragma unroll
        for (int vt = 0; vt < 4; ++vt)
            #pragma unroll
            for (int ot = 0; ot < 4; ++ot) {
                int o = ot * 16 + lr;
                bf16x8 wf0 = *(const bf16x8*)(wqp + o * 64 + lg * 8);
                bf16x8 wf1 = *(const bf16x8*)(wqp + o * 64 + 32 + lg * 8);
                f32x4 z = {};
                z = __builtin_amdgcn_mfma_f32_16x16x32_bf16(xn[vt][0], wf0, z, 0, 0, 0);
                z = __builtin_amdgcn_mfma_f32_16x16x32_bf16(xn[vt][1], wf1, z, 0, 0, 0);
                us4 pk = { f2bf(z[0]), f2bf(z[1]), f2bf(z[2]), f2bf(z[3]) };
                *(us4*)&Zt[o * ZLD + vzb + vt * 16 + lg * 4] = pk;
            }
    };
    auto pptr = [&](int j, int mt) -> const ushortT* {
        int q = 1 + (j >> 1), ch = j & 1;
        return P + (size_t)q * SZ + (size_t)(wbase + mt * 16 + lr) * 512 + ch * 256 + lg * 8;
    };

    xload(half);
    zphase(0);
    xload(0);
    __syncthreads();
    #pragma unroll
    for (int mt = 0; mt < 4; ++mt)
        #pragma unroll
        for (int ot = 0; ot < 4; ++ot) {
            int o = ot * 16 + lr;
            us4 z4 = *(const us4*)&Zt[o * ZLD + wave * 64 + mt * 16 + lg * 4];
            oacc[mt][ot][0] = bf2f(z4[0]);
            oacc[mt][ot][1] = bf2f(z4[1]);
            oacc[mt][ot][2] = bf2f(z4[2]);
            oacc[mt][ot][3] = bf2f(z4[3]);
        }
    __syncthreads();

    #pragma unroll 1
    for (int j = 0; j < 18; ++j) {
        int q = 1 + (j >> 1);
        zphase(q);
        int jn = (j < 17) ? j + 1 : 17;
        xload(jn & 1);
        __syncthreads();
        const ushortT* pc0 = pptr(j, 0);
        const ushortT* pc1 = pptr(j, 1);
        const ushortT* pc2 = pptr(j, 2);
        const ushortT* pc3 = pptr(j, 3);
        #pragma unroll
        for (int kk = 0; kk < 8; ++kk) {
            bf16x8 a0 = *(const bf16x8*)(pc0 + kk * 32);
            bf16x8 a1 = *(const bf16x8*)(pc1 + kk * 32);
            bf16x8 a2 = *(const bf16x8*)(pc2 + kk * 32);
            bf16x8 a3 = *(const bf16x8*)(pc3 + kk * 32);
            int vb = kk * 32 + lg * 8;
            bf16x8 b0 = *(const bf16x8*)&Zt[(0 * 16 + lr) * ZLD + vb];
            bf16x8 b1 = *(const bf16x8*)&Zt[(1 * 16 + lr) * ZLD + vb];
            bf16x8 b2 = *(const bf16x8*)&Zt[(2 * 16 + lr) * ZLD + vb];
            bf16x8 b3 = *(const bf16x8*)&Zt[(3 * 16 + lr) * ZLD + vb];
            oacc[0][0] = __builtin_amdgcn_mfma_f32_16x16x32_bf16(a0, b0, oacc[0][0], 0, 0, 0);
            oacc[1][0] = __builtin_amdgcn_mfma_f32_16x16x32_bf16(a1, b0, oacc[1][0], 0, 0, 0);
            oacc[2][0] = __builtin_amdgcn_mfma_f32_16x16x32_bf16(a2, b0, oacc[2][0], 0, 0, 0);
            oacc[3][0] = __builtin_amdgcn_mfma_f32_16x16x32_bf16(a3, b0, oacc[3][0], 0, 0, 0);
            oacc[0][1] = __builtin_amdgcn_mfma_f32_16x16x32_bf16(a0, b1, oacc[0][1], 0, 0, 0);
            oacc[1][1] = __builtin_amdgcn_mfma_f32_16x16x32_bf16(a1, b1, oacc[1][1], 0, 0, 0);
            oacc[2][1] = __builtin_amdgcn_mfma_f32_16x16x32_bf16(a2, b1, oacc[2][1], 0, 0, 0);
            oacc[3][1] = __builtin_amdgcn_mfma_f32_16x16x32_bf16(a3, b1, oacc[3][1], 0, 0, 0);
            oacc[0][2] = __builtin_amdgcn_mfma_f32_16x16x32_bf16(a0, b2, oacc[0][2], 0, 0, 0);
            oacc[1][2] = __builtin_amdgcn_mfma_f32_16x16x32_bf16(a1, b2, oacc[1][2], 0, 0, 0);
            oacc[2][2] = __builtin_amdgcn_mfma_f32_16x16x32_bf16(a2, b2, oacc[2][2], 0, 0, 0);
            oacc[3][2] = __builtin_amdgcn_mfma_f32_16x16x32_bf16(a3, b2, oacc[3][2], 0, 0, 0);
            oacc[0][3] = __builtin_amdgcn_mfma_f32_16x16x32_bf16(a0, b3, oacc[0][3], 0, 0, 0);
            oacc[1][3] = __builtin_amdgcn_mfma_f32_16x16x32_bf16(a1, b3, oacc[1][3], 0, 0, 0);
            oacc[2][3] = __builtin_amdgcn_mfma_f32_16x16x32_bf16(a2, b3, oacc[2][3], 0, 0, 0);
            oacc[3][3] = __builtin_amdgcn_mfma_f32_16x16x32_bf16(a3, b3, oacc[3][3], 0, 0, 0);
        }
        __syncthreads();
    }

    #pragma unroll
    for (int mt = 0; mt < 4; ++mt)
        #pragma unroll
        for (int ot = 0; ot < 4; ++ot)
            #pragma unroll
            for (int r = 0; r < 4; ++r) {
                int w = wbase + mt * 16 + lg * 4 + r;
                int o = ot * 16 + lr;
                size_t oi = (((size_t)b * 512 + w) * 12 + tt) * 64 + o;
                float v = oacc[mt][ot][r] + x[oi] + bias[o];
                out[oi] = (v > 0.f) ? v : 0.f;
            }
}

// ---------------------------------------------------------------------------
extern "C" void kernel_launch(void* const* d_in, const int* in_sizes, int n_in,
                              void* d_out, int out_size, void* d_ws, size_t ws_size,
                              hipStream_t stream) {
    const float* x    = (const float*)d_in[0];
    const float* adj  = (const float*)d_in[1];
    const float* emb  = (const float*)d_in[2];
    const float* W1   = (const float*)d_in[3];
    const float* W2   = (const float*)d_in[4];
    const float* mlpw = (const float*)d_in[5];
    const float* mlpb = (const float*)d_in[6];
    float* out = (float*)d_out;

    char* ws = (char*)d_ws;
    float*   e1   = (float*)(ws + 0);
    float*   e2   = (float*)(ws + 65536);
    float*   A    = (float*)(ws + 131072);
    float*   dvec = (float*)(ws + 1179648);
    ushortT* P    = (ushortT*)(ws + 1183744);   // [10][512][512] bf16 (slot0 = I)
    ushortT* Wq   = (ushortT*)(ws + 6426624);   // [10][64][64]  bf16
    ushortT* Z    = (ushortT*)(ws + 6508544);   // B' slab buffer
    const size_t ZOFF = 6508544;
    const size_t ZFULL = (size_t)24576 * KTOT * 2;   // 251.7 MB
    const size_t XBFSZ = (size_t)384 * 512 * 64 * 2; // 24 MB
    ushortT* xbf = (ushortT*)(ws + ZOFF + ZFULL);

    int nslab = 1;
    while (nslab <= 8 && ws_size < ZOFF + ZFULL / (size_t)nslab) nslab <<= 1;
    const bool use_xbf = (nslab == 1) && (ws_size >= ZOFF + ZFULL + XBFSZ);

    if (use_xbf) k_prep<<<12288, 256, 0, stream>>>(x, xbf);
    k_embed<<<2, 256, 0, stream>>>(emb, W1, W2, e1, e2);
    k_adj<<<512, 256, 0, stream>>>(adj, e1, e2, A, dvec);
    k_m<<<672, 256, 0, stream>>>(A, dvec, P, mlpw, Wq);

    const int SZ = 512 * 512;
    ushortT *S1 = P + 1 * SZ, *S2 = P + 2 * SZ, *S3 = P + 3 * SZ, *S4 = P + 4 * SZ,
            *S5 = P + 5 * SZ, *S6 = P + 6 * SZ, *S7 = P + 7 * SZ, *S8 = P + 8 * SZ,
            *S9 = P + 9 * SZ;
    // S2 = M^2 ; S4 = 2M^2 - I (T2^T)
    k_gemm512<<<64, 256, 0, stream>>>(S1, S1, S2, S4, 1, nullptr, nullptr, nullptr, nullptr);
    // S3 = M^3 ; S7 = 4M^3 - 3M (T3^T)  ||  S5 = (T2^T)^2
    k_gemm512<<<128, 256, 0, stream>>>(S1, S2, S3, S7, 2, S1, S4, S4, S5);
    // S6 = (T2^T)^3  ||  S8 = (T3^T)^2
    k_gemm512<<<128, 256, 0, stream>>>(S4, S5, S6, nullptr, 0, nullptr, S7, S7, S8);
    // S9 = (T3^T)^3
    k_gemm512<<<64, 256, 0, stream>>>(S7, S8, S9, nullptr, 0, nullptr, nullptr, nullptr, nullptr);

    if (nslab <= 8) {
        int btps = 384 / nslab;
        for (int s = 0; s < nslab; ++s) {
            if (use_xbf)
                k_z<true><<<btps * 2, 256, 0, stream>>>(x, xbf, Wq, Z, s * btps);
            else
                k_z<false><<<btps * 2, 256, 0, stream>>>(x, nullptr, Wq, Z, s * btps);
            k_big<<<btps * 2, 256, 0, stream>>>(P, Z, x, mlpb, out, s * btps);
        }
    } else {
        k_main_fb<<<768, 256, 0, stream>>>(x, P, Wq, mlpb, out);
    }
    (void)in_sizes; (void)n_in; (void)out_size;
}

// Round 16
// 324.652 us; speedup vs baseline: 1.1555x; 1.1555x over previous
//
#include <hip/hip_runtime.h>
#include <hip/hip_bf16.h>

typedef unsigned short ushortT;
typedef unsigned int uintT;
typedef __attribute__((ext_vector_type(8))) short bf16x8;
typedef __attribute__((ext_vector_type(4))) float f32x4;
typedef __attribute__((ext_vector_type(4))) unsigned short us4;
typedef __attribute__((ext_vector_type(8))) unsigned short us8;

__device__ __forceinline__ ushortT f2bf(float f) {
    union { float f; uintT u; } x; x.f = f;
    uintT r = x.u + 0x7fffu + ((x.u >> 16) & 1u);
    return (ushortT)(r >> 16);
}
__device__ __forceinline__ float bf2f(ushortT u) {
    union { uintT u; float f; } x; x.u = ((uintT)u) << 16; return x.f;
}

#define ZLD 260      // k_z LDS row stride (0-conflict family)
#define KTOT 5120    // K = 10 q * 512 v

// ---------------------------------------------------------------------------
// K0: column-softmax of W1/W2, e = emb @ sW, row-normalize.  grid=2 (e1, e2)
// ---------------------------------------------------------------------------
__global__ __launch_bounds__(256) void k_embed(const float* __restrict__ emb,
                                               const float* __restrict__ W1,
                                               const float* __restrict__ W2,
                                               float* __restrict__ e1,
                                               float* __restrict__ e2) {
    __shared__ float sW[800];
    __shared__ float sWs[800];
    const float* W = (blockIdx.x == 0) ? W1 : W2;
    float* e = (blockIdx.x == 0) ? e1 : e2;
    int tid = threadIdx.x;
    for (int i = tid; i < 800; i += 256) sW[i] = W[i];
    __syncthreads();
    if (tid < 20) {
        float mx = -1e30f;
        for (int i = 0; i < 40; ++i) mx = fmaxf(mx, sW[i * 20 + tid]);
        float s = 0.f;
        for (int i = 0; i < 40; ++i) s += __expf(sW[i * 20 + tid] - mx);
        float inv = 1.f / s;
        for (int i = 0; i < 40; ++i) sWs[i * 20 + tid] = __expf(sW[i * 20 + tid] - mx) * inv;
    }
    __syncthreads();
    for (int row = tid; row < 512; row += 256) {
        float acc[20];
        #pragma unroll
        for (int j = 0; j < 20; ++j) acc[j] = 0.f;
        for (int i = 0; i < 40; ++i) {
            float ev = emb[row * 40 + i];
            #pragma unroll
            for (int j = 0; j < 20; ++j) acc[j] += ev * sWs[i * 20 + j];
        }
        float s = 0.f;
        #pragma unroll
        for (int j = 0; j < 20; ++j) s += acc[j] * acc[j];
        float scale = 1.f / (sqrtf(s) + 1e-8f);
        #pragma unroll
        for (int j = 0; j < 20; ++j) e[row * 20 + j] = acc[j] * scale;
    }
}

// ---------------------------------------------------------------------------
// K1: A[v][w] = adj>0 ? e1[v].e2[w] + adj : 9e-15 ; d[v] = 1/sqrt(rowsum)
// ---------------------------------------------------------------------------
__global__ __launch_bounds__(256) void k_adj(const float* __restrict__ adj,
                                             const float* __restrict__ e1,
                                             const float* __restrict__ e2,
                                             float* __restrict__ A,
                                             float* __restrict__ d) {
    int v = blockIdx.x, tid = threadIdx.x;
    __shared__ float ev[20];
    if (tid < 20) ev[tid] = e1[v * 20 + tid];
    __syncthreads();
    float local = 0.f;
    for (int w = tid; w < 512; w += 256) {
        float dot = 0.f;
        #pragma unroll
        for (int j = 0; j < 20; ++j) dot += ev[j] * e2[w * 20 + j];
        float av = adj[v * 512 + w];
        float Av = (av > 0.f) ? (dot + av) : 9e-15f;
        A[v * 512 + w] = Av;
        local += Av;
    }
    __shared__ float red[256];
    red[tid] = local;
    __syncthreads();
    for (int s = 128; s > 0; s >>= 1) {
        if (tid < s) red[tid] += red[tid + s];
        __syncthreads();
    }
    if (tid == 0) d[v] = 1.f / sqrtf(red[0]);
}

// ---------------------------------------------------------------------------
// K2 (merged): blocks 0..511: P slot0 = I, slot1 = Ls^T.  blocks 512..671: Wq.
// ---------------------------------------------------------------------------
__global__ __launch_bounds__(256) void k_m(const float* __restrict__ A,
                                           const float* __restrict__ d,
                                           ushortT* __restrict__ P,
                                           const float* __restrict__ mlp_w,
                                           ushortT* __restrict__ Wq) {
    int bx = blockIdx.x, tid = threadIdx.x;
    if (bx < 512) {
        int w = bx;
        float dw = d[w];
        for (int v = tid; v < 512; v += 256) {
            float val = -d[v] * dw * A[v * 512 + w];
            P[512 * 512 + w * 512 + v] = f2bf(val);
            P[w * 512 + v] = (v == w) ? (ushortT)0x3F80 : (ushortT)0;
        }
    } else {
        int idx = (bx - 512) * 256 + tid;
        if (idx >= 10 * 64 * 64) return;
        int q = idx >> 12, rem = idx & 4095, o = rem >> 6, c = rem & 63;
        float v;
        if (q == 0) {
            v = 0.f;
            #pragma unroll
            for (int k = 0; k < 4; ++k) v += mlp_w[o * 832 + k * 64 + c];
        } else {
            v = mlp_w[o * 832 + (q + 3) * 64 + c];
        }
        Wq[idx] = f2bf(v);
    }
}

// ---------------------------------------------------------------------------
// 512x512x512 bf16 MFMA GEMM (+Chebyshev epilogue). Supports a second
// independent GEMM in blocks 64..127 (A2/B2/out3, mode 0).
// ---------------------------------------------------------------------------
__global__ __launch_bounds__(256) void k_gemm512(const ushortT* __restrict__ A,
                                                 const ushortT* __restrict__ B,
                                                 ushortT* __restrict__ out1,
                                                 ushortT* __restrict__ out2,
                                                 int mode,
                                                 const ushortT* __restrict__ aux,
                                                 const ushortT* __restrict__ A2,
                                                 const ushortT* __restrict__ B2,
                                                 ushortT* __restrict__ out3) {
    int bx = blockIdx.x;
    if (bx >= 64) { A = A2; B = B2; out1 = out3; out2 = nullptr; mode = 0; bx -= 64; }
    int wave = threadIdx.x >> 6, lane = threadIdx.x & 63;
    int lr = lane & 15, lg = lane >> 4;
    int mbase = (bx >> 3) * 64;
    int nbase = (bx & 7) * 64 + wave * 16;
    f32x4 acc[4] = {};
    for (int kk = 0; kk < 16; ++kk) {
        int k0 = kk * 32 + lg * 8;
        bf16x8 bfr;
        #pragma unroll
        for (int j = 0; j < 8; ++j) bfr[j] = (short)B[(k0 + j) * 512 + nbase + lr];
        #pragma unroll
        for (int wt = 0; wt < 4; ++wt) {
            bf16x8 af = *(const bf16x8*)(A + (mbase + wt * 16 + lr) * 512 + k0);
            acc[wt] = __builtin_amdgcn_mfma_f32_16x16x32_bf16(af, bfr, acc[wt], 0, 0, 0);
        }
    }
    #pragma unroll
    for (int wt = 0; wt < 4; ++wt)
        #pragma unroll
        for (int r = 0; r < 4; ++r) {
            int row = mbase + wt * 16 + lg * 4 + r;
            int col = nbase + lr;
            float v = acc[wt][r];
            out1[row * 512 + col] = f2bf(v);
            if (mode == 1) out2[row * 512 + col] = f2bf(2.f * v - (row == col ? 1.f : 0.f));
            else if (mode == 2) out2[row * 512 + col] = f2bf(4.f * v - 3.f * bf2f(aux[row * 512 + col]));
        }
}

// ---------------------------------------------------------------------------
// k_z: build B' = Z^T.  Z[n = btl*64+o][k = q*512+v] = sum_c x[bt,v,c]*Wq[o,c]
// (R11 verbatim: f32 x reads, MFMA z-compute, LDS transpose, 16B streams out)
// ---------------------------------------------------------------------------
__global__ __launch_bounds__(256) void k_z(const float* __restrict__ x,
                                           const ushortT* __restrict__ Wq,
                                           ushortT* __restrict__ Z,
                                           int slab0) {
    __shared__ ushortT Zl[64 * ZLD];
    int bid = blockIdx.x;
    int btl = bid >> 1, chunk = bid & 1;
    int bt = slab0 + btl;
    int b = bt / 12, t = bt - b * 12;
    int tid = threadIdx.x, wave = tid >> 6, lane = tid & 63;
    int lr = lane & 15, lg = lane >> 4;

    bf16x8 xn[4][2];
    const float* xb = x + ((size_t)b * 512 * 12 + t) * 64;
    #pragma unroll
    for (int vt = 0; vt < 4; ++vt) {
        int vrow = chunk * 256 + wave * 64 + vt * 16 + lr;
        const float* px = xb + (size_t)vrow * 768 + lg * 8;
        f32x4 f0 = *(const f32x4*)px;
        f32x4 f1 = *(const f32x4*)(px + 4);
        f32x4 f2 = *(const f32x4*)(px + 32);
        f32x4 f3 = *(const f32x4*)(px + 36);
        bf16x8 v0, v1;
        v0[0] = (short)f2bf(f0[0]); v0[1] = (short)f2bf(f0[1]);
        v0[2] = (short)f2bf(f0[2]); v0[3] = (short)f2bf(f0[3]);
        v0[4] = (short)f2bf(f1[0]); v0[5] = (short)f2bf(f1[1]);
        v0[6] = (short)f2bf(f1[2]); v0[7] = (short)f2bf(f1[3]);
        v1[0] = (short)f2bf(f2[0]); v1[1] = (short)f2bf(f2[1]);
        v1[2] = (short)f2bf(f2[2]); v1[3] = (short)f2bf(f2[3]);
        v1[4] = (short)f2bf(f3[0]); v1[5] = (short)f2bf(f3[1]);
        v1[6] = (short)f2bf(f3[2]); v1[7] = (short)f2bf(f3[3]);
        xn[vt][0] = v0;
        xn[vt][1] = v1;
    }

    #pragma unroll 1
    for (int q = 0; q < 10; ++q) {
        const ushortT* wqp = Wq + q * 4096;
        #pragma unroll
        for (int ot = 0; ot < 4; ++ot) {
            int o = ot * 16 + lr;
            bf16x8 wf0 = *(const bf16x8*)(wqp + o * 64 + lg * 8);
            bf16x8 wf1 = *(const bf16x8*)(wqp + o * 64 + 32 + lg * 8);
            #pragma unroll
            for (int vt = 0; vt < 4; ++vt) {
                f32x4 z = {};
                z = __builtin_amdgcn_mfma_f32_16x16x32_bf16(xn[vt][0], wf0, z, 0, 0, 0);
                z = __builtin_amdgcn_mfma_f32_16x16x32_bf16(xn[vt][1], wf1, z, 0, 0, 0);
                us4 pk = { f2bf(z[0]), f2bf(z[1]), f2bf(z[2]), f2bf(z[3]) };
                *(us4*)&Zl[o * ZLD + wave * 64 + vt * 16 + lg * 4] = pk;
            }
        }
        __syncthreads();
        size_t kbase = (size_t)q * 512 + chunk * 256;
        #pragma unroll
        for (int j = 0; j < 8; ++j) {
            int flat = j * 256 + tid;
            int o = flat >> 5, slot = flat & 31;
            us4 lo = *(const us4*)&Zl[o * ZLD + slot * 8];
            us4 hi = *(const us4*)&Zl[o * ZLD + slot * 8 + 4];
            us8 val = { lo[0], lo[1], lo[2], lo[3], hi[0], hi[1], hi[2], hi[3] };
            *(us8*)&Z[(size_t)(btl * 64 + o) * KTOT + kbase + slot * 8] = val;
        }
        __syncthreads();
    }
}

// ---------------------------------------------------------------------------
// k_big (R11 verbatim — best measured: 204us, MfmaUtil 25-27%):
// T3/T4 counted-vmcnt pipeline. 3-deep LDS stage ring (48KB), raw s_barrier
// pairs, vmcnt(8) steady-state at phase TOP (never 0 in main loop; stages for
// kt+1,kt+2 stay in flight -> 3-phase HBM latency cover), linear LDS layout,
// 3 blocks/CU.
// ---------------------------------------------------------------------------
__global__ __launch_bounds__(256) void k_big(const ushortT* __restrict__ P,
                                             const ushortT* __restrict__ Z,
                                             const float* __restrict__ x,
                                             const float* __restrict__ bias,
                                             float* __restrict__ out,
                                             int slab0) {
    __shared__ ushortT SA[3][4096];   // [ring][128 m x 32 k] linear
    __shared__ ushortT SB[3][4096];   // [ring][128 n x 32 k] linear
    int nwg = (int)gridDim.x;
    int bid = (int)blockIdx.x;
    int cpx = nwg >> 3;                               // blocks per XCD chunk
    int lbid = (bid & 7) * cpx + (bid >> 3);          // bijective (nwg%8==0)
    int mblk = lbid & 3;                              // m fastest -> same XCD
    int nblk = lbid >> 2;
    int mbase = mblk * 128;
    int n0 = nblk * 128;
    int tid = threadIdx.x, wave = tid >> 6, lane = tid & 63;
    int lr = lane & 15, lg = lane >> 4;
    int wm = wave >> 1, wn = wave & 1;
    int srow = tid >> 2, sg = tid & 3;                // staging row/group

    f32x4 acc[4][4] = {};

    // stage K-step kt into ring buffer buf (A: P rows, B: Z rows). 4 VMEM/wave.
    auto stage = [&](int kt, int buf) {
        int q = kt >> 4;
        int v0 = (kt & 15) * 32;
        const ushortT* Pk = P + (size_t)q * 262144 + v0 + sg * 8;
        const ushortT* Zk = Z + (size_t)kt * 32 + sg * 8;
        #pragma unroll
        for (int i = 0; i < 2; ++i) {
            int row = i * 64 + srow;
            __builtin_amdgcn_global_load_lds(Pk + (size_t)(mbase + row) * 512,
                                             &SA[buf][(i * 256 + wave * 64) * 8], 16, 0, 0);
            __builtin_amdgcn_global_load_lds(Zk + (size_t)(n0 + row) * KTOT,
                                             &SB[buf][(i * 256 + wave * 64) * 8], 16, 0, 0);
        }
    };

    // one pipeline phase. wsel: 0 -> vmcnt(8), 1 -> vmcnt(4), 2 -> vmcnt(0).
    auto phase = [&](int kt, int wsel) {
        if (wsel == 0)      asm volatile("s_waitcnt vmcnt(8)" ::: "memory");
        else if (wsel == 1) asm volatile("s_waitcnt vmcnt(4)" ::: "memory");
        else                asm volatile("s_waitcnt vmcnt(0)" ::: "memory");
        __builtin_amdgcn_sched_barrier(0);
        __builtin_amdgcn_s_barrier();          // all waves: kt data resident
        __builtin_amdgcn_sched_barrier(0);
        int buf = kt % 3;
        bf16x8 af[4], bfr[4];
        #pragma unroll
        for (int mt = 0; mt < 4; ++mt) {
            int m = wm * 64 + mt * 16 + lr;
            af[mt] = *(const bf16x8*)&SA[buf][m * 32 + lg * 8];
        }
        #pragma unroll
        for (int nt = 0; nt < 4; ++nt) {
            int n = wn * 64 + nt * 16 + lr;
            bfr[nt] = *(const bf16x8*)&SB[buf][n * 32 + lg * 8];
        }
        __builtin_amdgcn_s_setprio(1);
        #pragma unroll
        for (int mt = 0; mt < 4; ++mt)
            #pragma unroll
            for (int nt = 0; nt < 4; ++nt)
                acc[mt][nt] = __builtin_amdgcn_mfma_f32_16x16x32_bf16(af[mt], bfr[nt], acc[mt][nt], 0, 0, 0);
        __builtin_amdgcn_s_setprio(0);
        __builtin_amdgcn_sched_barrier(0);
        __builtin_amdgcn_s_barrier();          // all waves done reading buf
        __builtin_amdgcn_sched_barrier(0);
        if (kt + 3 < 160) stage(kt + 3, (kt + 3) % 3);
    };

    // prologue: fill the 3-deep ring (12 loads/wave outstanding)
    stage(0, 0);
    __builtin_amdgcn_sched_barrier(0);
    stage(1, 1);
    __builtin_amdgcn_sched_barrier(0);
    stage(2, 2);
    __builtin_amdgcn_sched_barrier(0);

    #pragma unroll 1
    for (int kt = 0; kt < 158; ++kt) phase(kt, 0);
    phase(158, 1);
    phase(159, 2);

    // ---- epilogue: residual + bias + relu ----
    #pragma unroll
    for (int mt = 0; mt < 4; ++mt)
        #pragma unroll
        for (int nt = 0; nt < 4; ++nt)
            #pragma unroll
            for (int r = 0; r < 4; ++r) {
                int m = mbase + wm * 64 + mt * 16 + lg * 4 + r;   // w
                int nf = n0 + wn * 64 + nt * 16 + lr;
                int btl = nf >> 6, o = nf & 63;
                int bt = slab0 + btl;
                int bb = bt / 12, t = bt - bb * 12;
                size_t oi = (((size_t)bb * 512 + m) * 12 + t) * 64 + o;
                float v = acc[mt][nt][r] + x[oi] + bias[o];
                out[oi] = (v > 0.f) ? v : 0.f;
            }
}

// ---------------------------------------------------------------------------
// Fallback fused kernel (R9 structure, f32 x path) — used only if ws is tiny.
// ---------------------------------------------------------------------------
__global__ __launch_bounds__(256, 2) void k_main_fb(const float* __restrict__ x,
                                                    const ushortT* __restrict__ P,
                                                    const ushortT* __restrict__ Wq,
                                                    const float* __restrict__ bias,
                                                    float* __restrict__ out) {
    __shared__ ushortT Zt[64 * ZLD];
    const int SZ = 512 * 512;
    int bid = blockIdx.x;
    int slot = bid & 7, idx = bid >> 3;
    int half = slot >> 2;
    int bt = idx * 4 + (slot & 3);
    int b = bt / 12, tt = bt - b * 12;
    int tid = threadIdx.x, wave = tid >> 6, lane = tid & 63;
    int lr = lane & 15, lg = lane >> 4;
    int wbase = half * 256 + wave * 64;
    int vzb = wave * 64;
    const float* xqf = x + ((size_t)b * 512 * 12 + tt) * 64;

    f32x4 oacc[4][4] = {};
    bf16x8 xn[4][2];

    auto xload = [&](int ch) {
        #pragma unroll
        for (int vt = 0; vt < 4; ++vt) {
            int vrow = ch * 256 + vzb + vt * 16 + lr;
            const float* px = xqf + (size_t)vrow * 768 + lg * 8;
            f32x4 f0 = *(const f32x4*)px;
            f32x4 f1 = *(const f32x4*)(px + 4);
            f32x4 f2 = *(const f32x4*)(px + 32);
            f32x4 f3 = *(const f32x4*)(px + 36);
            bf16x8 v0, v1;
            v0[0] = (short)f2bf(f0[0]); v0[1] = (short)f2bf(f0[1]);
            v0[2] = (short)f2bf(f0[2]); v0[3] = (short)f2bf(f0[3]);
            v0[4] = (short)f2bf(f1[0]); v0[5] = (short)f2bf(f1[1]);
            v0[6] = (short)f2bf(f1[2]); v0[7] = (short)f2bf(f1[3]);
            v1[0] = (short)f2bf(f2[0]); v1[1] = (short)f2bf(f2[1]);
            v1[2] = (short)f2bf(f2[2]); v1[3] = (short)f2bf(f2[3]);
            v1[4] = (short)f2bf(f3[0]); v1[5] = (short)f2bf(f3[1]);
            v1[6] = (short)f2bf(f3[2]); v1[7] = (short)f2bf(f3[3]);
            xn[vt][0] = v0;
            xn[vt][1] = v1;
        }
    };
    auto zphase = [&](int q) {
        const ushortT* wqp = Wq + q * 4096;
        #pragma unroll
        for (int vt = 0; vt < 4; ++vt)
            #pragma unroll
            for (int ot = 0; ot < 4; ++ot) {
                int o = ot * 16 + lr;
                bf16x8 wf0 = *(const bf16x8*)(wqp + o * 64 + lg * 8);
                bf16x8 wf1 = *(const bf16x8*)(wqp + o * 64 + 32 + lg * 8);
                f32x4 z = {};
                z = __builtin_amdgcn_mfma_f32_16x16x32_bf16(xn[vt][0], wf0, z, 0, 0, 0);
                z = __builtin_amdgcn_mfma_f32_16x16x32_bf16(xn[vt][1], wf1, z, 0, 0, 0);
                us4 pk = { f2bf(z[0]), f2bf(z[1]), f2bf(z[2]), f2bf(z[3]) };
                *(us4*)&Zt[o * ZLD + vzb + vt * 16 + lg * 4] = pk;
            }
    };
    auto pptr = [&](int j, int mt) -> const ushortT* {
        int q = 1 + (j >> 1), ch = j & 1;
        return P + (size_t)q * SZ + (size_t)(wbase + mt * 16 + lr) * 512 + ch * 256 + lg * 8;
    };

    xload(half);
    zphase(0);
    xload(0);
    __syncthreads();
    #pragma unroll
    for (int mt = 0; mt < 4; ++mt)
        #pragma unroll
        for (int ot = 0; ot < 4; ++ot) {
            int o = ot * 16 + lr;
            us4 z4 = *(const us4*)&Zt[o * ZLD + wave * 64 + mt * 16 + lg * 4];
            oacc[mt][ot][0] = bf2f(z4[0]);
            oacc[mt][ot][1] = bf2f(z4[1]);
            oacc[mt][ot][2] = bf2f(z4[2]);
            oacc[mt][ot][3] = bf2f(z4[3]);
        }
    __syncthreads();

    #pragma unroll 1
    for (int j = 0; j < 18; ++j) {
        int q = 1 + (j >> 1);
        zphase(q);
        int jn = (j < 17) ? j + 1 : 17;
        xload(jn & 1);
        __syncthreads();
        const ushortT* pc0 = pptr(j, 0);
        const ushortT* pc1 = pptr(j, 1);
        const ushortT* pc2 = pptr(j, 2);
        const ushortT* pc3 = pptr(j, 3);
        #pragma unroll
        for (int kk = 0; kk < 8; ++kk) {
            bf16x8 a0 = *(const bf16x8*)(pc0 + kk * 32);
            bf16x8 a1 = *(const bf16x8*)(pc1 + kk * 32);
            bf16x8 a2 = *(const bf16x8*)(pc2 + kk * 32);
            bf16x8 a3 = *(const bf16x8*)(pc3 + kk * 32);
            int vb = kk * 32 + lg * 8;
            bf16x8 b0 = *(const bf16x8*)&Zt[(0 * 16 + lr) * ZLD + vb];
            bf16x8 b1 = *(const bf16x8*)&Zt[(1 * 16 + lr) * ZLD + vb];
            bf16x8 b2 = *(const bf16x8*)&Zt[(2 * 16 + lr) * ZLD + vb];
            bf16x8 b3 = *(const bf16x8*)&Zt[(3 * 16 + lr) * ZLD + vb];
            oacc[0][0] = __builtin_amdgcn_mfma_f32_16x16x32_bf16(a0, b0, oacc[0][0], 0, 0, 0);
            oacc[1][0] = __builtin_amdgcn_mfma_f32_16x16x32_bf16(a1, b0, oacc[1][0], 0, 0, 0);
            oacc[2][0] = __builtin_amdgcn_mfma_f32_16x16x32_bf16(a2, b0, oacc[2][0], 0, 0, 0);
            oacc[3][0] = __builtin_amdgcn_mfma_f32_16x16x32_bf16(a3, b0, oacc[3][0], 0, 0, 0);
            oacc[0][1] = __builtin_amdgcn_mfma_f32_16x16x32_bf16(a0, b1, oacc[0][1], 0, 0, 0);
            oacc[1][1] = __builtin_amdgcn_mfma_f32_16x16x32_bf16(a1, b1, oacc[1][1], 0, 0, 0);
            oacc[2][1] = __builtin_amdgcn_mfma_f32_16x16x32_bf16(a2, b1, oacc[2][1], 0, 0, 0);
            oacc[3][1] = __builtin_amdgcn_mfma_f32_16x16x32_bf16(a3, b1, oacc[3][1], 0, 0, 0);
            oacc[0][2] = __builtin_amdgcn_mfma_f32_16x16x32_bf16(a0, b2, oacc[0][2], 0, 0, 0);
            oacc[1][2] = __builtin_amdgcn_mfma_f32_16x16x32_bf16(a1, b2, oacc[1][2], 0, 0, 0);
            oacc[2][2] = __builtin_amdgcn_mfma_f32_16x16x32_bf16(a2, b2, oacc[2][2], 0, 0, 0);
            oacc[3][2] = __builtin_amdgcn_mfma_f32_16x16x32_bf16(a3, b2, oacc[3][2], 0, 0, 0);
            oacc[0][3] = __builtin_amdgcn_mfma_f32_16x16x32_bf16(a0, b3, oacc[0][3], 0, 0, 0);
            oacc[1][3] = __builtin_amdgcn_mfma_f32_16x16x32_bf16(a1, b3, oacc[1][3], 0, 0, 0);
            oacc[2][3] = __builtin_amdgcn_mfma_f32_16x16x32_bf16(a2, b3, oacc[2][3], 0, 0, 0);
            oacc[3][3] = __builtin_amdgcn_mfma_f32_16x16x32_bf16(a3, b3, oacc[3][3], 0, 0, 0);
        }
        __syncthreads();
    }

    #pragma unroll
    for (int mt = 0; mt < 4; ++mt)
        #pragma unroll
        for (int ot = 0; ot < 4; ++ot)
            #pragma unroll
            for (int r = 0; r < 4; ++r) {
                int w = wbase + mt * 16 + lg * 4 + r;
                int o = ot * 16 + lr;
                size_t oi = (((size_t)b * 512 + w) * 12 + tt) * 64 + o;
                float v = oacc[mt][ot][r] + x[oi] + bias[o];
                out[oi] = (v > 0.f) ? v : 0.f;
            }
}

// ---------------------------------------------------------------------------
extern "C" void kernel_launch(void* const* d_in, const int* in_sizes, int n_in,
                              void* d_out, int out_size, void* d_ws, size_t ws_size,
                              hipStream_t stream) {
    const float* x    = (const float*)d_in[0];
    const float* adj  = (const float*)d_in[1];
    const float* emb  = (const float*)d_in[2];
    const float* W1   = (const float*)d_in[3];
    const float* W2   = (const float*)d_in[4];
    const float* mlpw = (const float*)d_in[5];
    const float* mlpb = (const float*)d_in[6];
    float* out = (float*)d_out;

    char* ws = (char*)d_ws;
    float*   e1   = (float*)(ws + 0);
    float*   e2   = (float*)(ws + 65536);
    float*   A    = (float*)(ws + 131072);
    float*   dvec = (float*)(ws + 1179648);
    ushortT* P    = (ushortT*)(ws + 1183744);   // [10][512][512] bf16 (slot0 = I)
    ushortT* Wq   = (ushortT*)(ws + 6426624);   // [10][64][64]  bf16
    ushortT* Z    = (ushortT*)(ws + 6508544);   // B' slab buffer
    const size_t ZOFF = 6508544;

    k_embed<<<2, 256, 0, stream>>>(emb, W1, W2, e1, e2);
    k_adj<<<512, 256, 0, stream>>>(adj, e1, e2, A, dvec);
    k_m<<<672, 256, 0, stream>>>(A, dvec, P, mlpw, Wq);

    const int SZ = 512 * 512;
    ushortT *S1 = P + 1 * SZ, *S2 = P + 2 * SZ, *S3 = P + 3 * SZ, *S4 = P + 4 * SZ,
            *S5 = P + 5 * SZ, *S6 = P + 6 * SZ, *S7 = P + 7 * SZ, *S8 = P + 8 * SZ,
            *S9 = P + 9 * SZ;
    // S2 = M^2 ; S4 = 2M^2 - I (T2^T)
    k_gemm512<<<64, 256, 0, stream>>>(S1, S1, S2, S4, 1, nullptr, nullptr, nullptr, nullptr);
    // S3 = M^3 ; S7 = 4M^3 - 3M (T3^T)  ||  S5 = (T2^T)^2
    k_gemm512<<<128, 256, 0, stream>>>(S1, S2, S3, S7, 2, S1, S4, S4, S5);
    // S6 = (T2^T)^3  ||  S8 = (T3^T)^2
    k_gemm512<<<128, 256, 0, stream>>>(S4, S5, S6, nullptr, 0, nullptr, S7, S7, S8);
    // S9 = (T3^T)^3
    k_gemm512<<<64, 256, 0, stream>>>(S7, S8, S9, nullptr, 0, nullptr, nullptr, nullptr, nullptr);

    const size_t ZFULL = (size_t)24576 * KTOT * 2;   // 251.7 MB
    int nslab = 1;
    while (nslab <= 8 && ws_size < ZOFF + ZFULL / (size_t)nslab) nslab <<= 1;

    if (nslab <= 8) {
        int btps = 384 / nslab;
        for (int s = 0; s < nslab; ++s) {
            k_z<<<btps * 2, 256, 0, stream>>>(x, Wq, Z, s * btps);
            k_big<<<btps * 2, 256, 0, stream>>>(P, Z, x, mlpb, out, s * btps);
        }
    } else {
        k_main_fb<<<768, 256, 0, stream>>>(x, P, Wq, mlpb, out);
    }
    (void)in_sizes; (void)n_in; (void)out_size;
}